// Round 1
// baseline (590.260 us; speedup 1.0000x reference)
//
#include <hip/hip_runtime.h>
#include <math.h>

// LRN on x[16,96,224,224] fp32.
// out = x * (2 + 1e-4 * boxfilter5x5(sum_c x^2))^(-0.75)
//
// Round 1 structure: 3 kernels, fully coalesced float4 streaming.
//   A : s[b,h,w]   = sum_c x^2          (read 308 MB, write 3.2 MB)
//   A2: sc[b,h,w]  = (2+1e-4*box(s))^-0.75  (3.2 MB R/W, L2-resident)
//   B : out = x * sc                    (read 311 MB, write 308 MB)

#define BB 16
#define CC 96
#define HH 224
#define WW 224
#define HW (HH * WW)          // 50176
#define CHW (CC * HW)         // 4816896
#define NPIX (BB * HW)        // 802816
#define W4 (WW / 4)           // 56
#define NCOL (BB * HH * W4)   // 200704 float4 columns per channel-plane

__global__ __launch_bounds__(256) void lrn_sqsum(const float* __restrict__ x,
                                                 float* __restrict__ s) {
    int t = blockIdx.x * blockDim.x + threadIdx.x;
    if (t >= NCOL) return;
    int w4 = t % W4;
    int bh = t / W4;              // b*HH + h
    int b  = bh / HH;
    int h  = bh % HH;
    size_t idx = (((size_t)b * CHW + (size_t)h * WW) >> 2) + w4;  // float4 index
    const float4* xp = (const float4*)x;
    float4 acc = make_float4(0.f, 0.f, 0.f, 0.f);
#pragma unroll 4
    for (int c = 0; c < CC; ++c) {
        float4 v = xp[idx + (size_t)c * (HW / 4)];
        acc.x += v.x * v.x;
        acc.y += v.y * v.y;
        acc.z += v.z * v.z;
        acc.w += v.w * v.w;
    }
    ((float4*)s)[t] = acc;        // s float4 index = bh*W4 + w4 = t
}

__global__ __launch_bounds__(256) void lrn_scale(const float* __restrict__ s,
                                                 float* __restrict__ sc) {
    int t = blockIdx.x * blockDim.x + threadIdx.x;
    if (t >= NPIX) return;
    int w  = t % WW;
    int bh = t / WW;              // b*HH + h
    int h  = bh % HH;
    float y = 0.f;
#pragma unroll
    for (int dh = -2; dh <= 2; ++dh) {
        int hh = h + dh;
        if (hh < 0 || hh >= HH) continue;          // zero padding (SAME)
        const float* row = s + (size_t)(bh + dh) * WW;  // same b guaranteed by hh bounds
#pragma unroll
        for (int dw = -2; dw <= 2; ++dw) {
            int ww = w + dw;
            if (ww >= 0 && ww < WW) y += row[ww];
        }
    }
    sc[t] = powf(2.0f + 1e-4f * y, -0.75f);
}

__global__ __launch_bounds__(256) void lrn_norm(const float* __restrict__ x,
                                                const float* __restrict__ sc,
                                                float* __restrict__ out) {
    int t = blockIdx.x * blockDim.x + threadIdx.x;
    if (t >= NCOL) return;
    int w4 = t % W4;
    int bh = t / W4;
    int b  = bh / HH;
    int h  = bh % HH;
    float4 scv = ((const float4*)sc)[t];
    size_t idx = (((size_t)b * CHW + (size_t)h * WW) >> 2) + w4;
    const float4* xp = (const float4*)x;
    float4* op = (float4*)out;
#pragma unroll 4
    for (int c = 0; c < CC; ++c) {
        size_t i = idx + (size_t)c * (HW / 4);
        float4 v = xp[i];
        v.x *= scv.x;
        v.y *= scv.y;
        v.z *= scv.z;
        v.w *= scv.w;
        op[i] = v;
    }
}

extern "C" void kernel_launch(void* const* d_in, const int* in_sizes, int n_in,
                              void* d_out, int out_size, void* d_ws, size_t ws_size,
                              hipStream_t stream) {
    const float* x = (const float*)d_in[0];
    float* out = (float*)d_out;
    float* s  = (float*)d_ws;          // NPIX floats = 3.2 MB
    float* sc = s + NPIX;              // NPIX floats = 3.2 MB (ws needs 6.4 MB)

    lrn_sqsum<<<(NCOL + 255) / 256, 256, 0, stream>>>(x, s);
    lrn_scale<<<(NPIX + 255) / 256, 256, 0, stream>>>(s, sc);
    lrn_norm<<<(NCOL + 255) / 256, 256, 0, stream>>>(x, sc, out);
}